// Round 3
// baseline (666.424 us; speedup 1.0000x reference)
//
#include <hip/hip_runtime.h>

#define N_NODES 100000
#define N_EDGES 600000
#define IN_CH 5
#define HID 128

// ---------------- edge dtype detection (int64 vs int32 layout) ----------------
// If edge_index is int64 (little-endian), every odd 32-bit word is a zero high
// word. If int32, odd words are real node ids (nonzero w.h.p. over 4096 samples).
__global__ __launch_bounds__(256) void k_detect(const unsigned* __restrict__ E, int* __restrict__ flag) {
    int t = blockIdx.x * blockDim.x + threadIdx.x;
    if (t < 4096) {
        if (E[2 * t + 1] != 0u) atomicOr(flag, 1);
    }
}

__device__ __forceinline__ int edge_elem(const unsigned* __restrict__ E, int elem, int is64) {
    return (int)E[is64 ? (2 * elem) : elem];
}

// ---------------- degree count ----------------
__global__ __launch_bounds__(256) void k_count(const unsigned* __restrict__ E, const int* __restrict__ flag,
                                               int* __restrict__ deg) {
    int e = blockIdx.x * blockDim.x + threadIdx.x;
    int is64 = (*flag == 0) ? 1 : 0;
    if (e < N_EDGES) {
        int d = edge_elem(E, N_EDGES + e, is64);
        atomicAdd(&deg[d], 1);
    }
}

// ---------------- exclusive scan (3-kernel), dinv fused into pass 1 ----------------
__global__ __launch_bounds__(256) void k_scan1(const int* __restrict__ deg, int* __restrict__ offs,
                                               int* __restrict__ bsum, float* __restrict__ dinv) {
    __shared__ int sd[256];
    int t = threadIdx.x;
    int base = blockIdx.x * 1024 + t * 4;
    int v0 = (base + 0 < N_NODES) ? deg[base + 0] : 0;
    int v1 = (base + 1 < N_NODES) ? deg[base + 1] : 0;
    int v2 = (base + 2 < N_NODES) ? deg[base + 2] : 0;
    int v3 = (base + 3 < N_NODES) ? deg[base + 3] : 0;
    if (base + 0 < N_NODES) dinv[base + 0] = rsqrtf((float)v0 + 1.0f);
    if (base + 1 < N_NODES) dinv[base + 1] = rsqrtf((float)v1 + 1.0f);
    if (base + 2 < N_NODES) dinv[base + 2] = rsqrtf((float)v2 + 1.0f);
    if (base + 3 < N_NODES) dinv[base + 3] = rsqrtf((float)v3 + 1.0f);
    sd[t] = v0 + v1 + v2 + v3;
    __syncthreads();
    for (int off = 1; off < 256; off <<= 1) {
        int x = sd[t];
        if (t >= off) x += sd[t - off];
        __syncthreads();
        sd[t] = x;
        __syncthreads();
    }
    int run = (t == 0) ? 0 : sd[t - 1];
    if (base + 0 < N_NODES) offs[base + 0] = run; run += v0;
    if (base + 1 < N_NODES) offs[base + 1] = run; run += v1;
    if (base + 2 < N_NODES) offs[base + 2] = run; run += v2;
    if (base + 3 < N_NODES) offs[base + 3] = run;
    if (t == 255) bsum[blockIdx.x] = sd[255];
}

__global__ __launch_bounds__(256) void k_scan2(int* __restrict__ bsum, int nb) {
    __shared__ int sd[256];
    int t = threadIdx.x;
    sd[t] = (t < nb) ? bsum[t] : 0;
    __syncthreads();
    for (int off = 1; off < 256; off <<= 1) {
        int x = sd[t];
        if (t >= off) x += sd[t - off];
        __syncthreads();
        sd[t] = x;
        __syncthreads();
    }
    if (t < nb) bsum[t] = (t == 0) ? 0 : sd[t - 1];
}

__global__ __launch_bounds__(256) void k_scan3(int* __restrict__ offs, const int* __restrict__ bsum) {
    int i = blockIdx.x * blockDim.x + threadIdx.x;
    if (i < N_NODES) offs[i] += bsum[i >> 10];
    if (i == 0) offs[N_NODES] = N_EDGES;
}

// ---------------- CSR fill ----------------
__global__ __launch_bounds__(256) void k_fill(const unsigned* __restrict__ E, const int* __restrict__ flag,
                                              const float* __restrict__ dinv, const int* __restrict__ offs,
                                              int* __restrict__ cursor, int* __restrict__ csr_src,
                                              float* __restrict__ csr_w) {
    int e = blockIdx.x * blockDim.x + threadIdx.x;
    int is64 = (*flag == 0) ? 1 : 0;
    if (e < N_EDGES) {
        int s = edge_elem(E, e, is64);
        int d = edge_elem(E, N_EDGES + e, is64);
        int p = atomicAdd(&cursor[d], 1);
        int idx = offs[d] + p;
        csr_src[idx] = s;
        csr_w[idx] = dinv[s] * dinv[d];
    }
}

// ---------------- layer 0: aggregate on 6-wide input ----------------
__global__ __launch_bounds__(256) void k_agg6(const float* __restrict__ x, const float* __restrict__ sdf,
                                              const float* __restrict__ dinv, const int* __restrict__ offs,
                                              const int* __restrict__ csr_src, const float* __restrict__ csr_w,
                                              float* __restrict__ g) {
    int i = blockIdx.x * blockDim.x + threadIdx.x;
    if (i >= N_NODES) return;
    float dn = dinv[i];
    float dn2 = dn * dn;
    float a[6];
#pragma unroll
    for (int f = 0; f < IN_CH; f++) a[f] = dn2 * x[i * IN_CH + f];
    a[5] = dn2 * sdf[i];
    int e0 = offs[i], e1 = offs[i + 1];
    for (int e = e0; e < e1; e++) {
        int s = csr_src[e];
        float w = csr_w[e];
#pragma unroll
        for (int f = 0; f < IN_CH; f++) a[f] += w * x[s * IN_CH + f];
        a[5] += w * sdf[s];
    }
#pragma unroll
    for (int f = 0; f < 6; f++) g[i * 6 + f] = a[f];
}

// ---------------- layer 0 GEMM: [N,6] @ [6,128] + b, relu ----------------
__global__ __launch_bounds__(256) void k_gemm6(const float* __restrict__ g, const float* __restrict__ W,
                                               const float* __restrict__ b, float* __restrict__ out) {
    __shared__ float Ws[6 * 128];
    __shared__ float bs[128];
    int t = threadIdx.x;
    for (int j = t; j < 768; j += 256) Ws[j] = W[j];
    if (t < 128) bs[t] = b[t];
    __syncthreads();
    int node = blockIdx.x * 2 + (t >> 7);
    int f = t & 127;
    if (node >= N_NODES) return;
    float acc = bs[f];
#pragma unroll
    for (int k = 0; k < 6; k++) acc += g[node * 6 + k] * Ws[k * 128 + f];
    out[node * 128 + f] = fmaxf(acc, 0.0f);
}

// ---------------- hidden GEMM: [N,128] @ [128,128] (no epilogue) ----------------
// 64-row x 128-col tile per 256-thread block; A staged transposed in LDS.
__global__ __launch_bounds__(256) void k_gemm128(const float* __restrict__ H, const float* __restrict__ W,
                                                 float* __restrict__ out) {
    __shared__ float At[32 * 68];   // [k][row], pad 64->68 keeps 16B alignment
    __shared__ float Bs[32 * 128];  // [k][col]
    int t = threadIdx.x;
    int tr = t >> 5;   // 0..7 -> rows tr*8..tr*8+7
    int tc = t & 31;   // cols tc*4..tc*4+3
    int row0 = blockIdx.x * 64;
    float acc[8][4];
#pragma unroll
    for (int r = 0; r < 8; r++)
#pragma unroll
        for (int c = 0; c < 4; c++) acc[r][c] = 0.0f;

    for (int kb = 0; kb < 4; kb++) {
        // stage A (64 rows x 32 k) transposed
#pragma unroll
        for (int j = 0; j < 2; j++) {
            int lin = t + j * 256;
            int r = lin >> 3;
            int kk = (lin & 7) * 4;
            float4 v = make_float4(0.f, 0.f, 0.f, 0.f);
            int grow = row0 + r;
            if (grow < N_NODES) v = *(const float4*)&H[(size_t)grow * 128 + kb * 32 + kk];
            At[(kk + 0) * 68 + r] = v.x;
            At[(kk + 1) * 68 + r] = v.y;
            At[(kk + 2) * 68 + r] = v.z;
            At[(kk + 3) * 68 + r] = v.w;
        }
        // stage B (32 k x 128 cols)
#pragma unroll
        for (int j = 0; j < 4; j++) {
            int lin = t + j * 256;
            int k = lin >> 5;
            int c = (lin & 31) * 4;
            *(float4*)&Bs[k * 128 + c] = *(const float4*)&W[(size_t)(kb * 32 + k) * 128 + c];
        }
        __syncthreads();
#pragma unroll
        for (int k = 0; k < 32; k++) {
            float4 a0 = *(const float4*)&At[k * 68 + tr * 8];
            float4 a1 = *(const float4*)&At[k * 68 + tr * 8 + 4];
            float4 bv = *(const float4*)&Bs[k * 128 + tc * 4];
            float ar[8] = {a0.x, a0.y, a0.z, a0.w, a1.x, a1.y, a1.z, a1.w};
            float bc[4] = {bv.x, bv.y, bv.z, bv.w};
#pragma unroll
            for (int r = 0; r < 8; r++)
#pragma unroll
                for (int c = 0; c < 4; c++) acc[r][c] += ar[r] * bc[c];
        }
        __syncthreads();
    }
#pragma unroll
    for (int r = 0; r < 8; r++) {
        int grow = row0 + tr * 8 + r;
        if (grow < N_NODES)
            *(float4*)&out[(size_t)grow * 128 + tc * 4] = make_float4(acc[r][0], acc[r][1], acc[r][2], acc[r][3]);
    }
}

// ---------------- hidden aggregation: wave per node, 128 feats as float2/lane ----------------
// One-edge lookahead so the next (src, w) loads issue before the current gather retires.
__global__ __launch_bounds__(256) void k_agg128(const float* __restrict__ xw, const float* __restrict__ bias,
                                                const float* __restrict__ dinv, const int* __restrict__ offs,
                                                const int* __restrict__ csr_src, const float* __restrict__ csr_w,
                                                float* __restrict__ out) {
    int w = threadIdx.x >> 6;
    int lane = threadIdx.x & 63;
    int node = blockIdx.x * 4 + w;
    if (node >= N_NODES) return;
    const float2* xw2 = (const float2*)xw;
    float dn = dinv[node];
    float2 v = xw2[(size_t)node * 64 + lane];
    float2 acc;
    acc.x = dn * dn * v.x;
    acc.y = dn * dn * v.y;
    int e0 = offs[node], e1 = offs[node + 1];
    if (e0 < e1) {
        int s = csr_src[e0];
        float wgt = csr_w[e0];
        for (int e = e0; e + 1 < e1; e++) {
            int s2 = csr_src[e + 1];
            float w2 = csr_w[e + 1];
            float2 u = xw2[(size_t)s * 64 + lane];
            acc.x += wgt * u.x;
            acc.y += wgt * u.y;
            s = s2;
            wgt = w2;
        }
        float2 u = xw2[(size_t)s * 64 + lane];
        acc.x += wgt * u.x;
        acc.y += wgt * u.y;
    }
    float2 bv = ((const float2*)bias)[lane];
    acc.x = fmaxf(acc.x + bv.x, 0.0f);
    acc.y = fmaxf(acc.y + bv.y, 0.0f);
    ((float2*)out)[(size_t)node * 64 + lane] = acc;
}

// ---------------- final GEMM: [N,128] @ [128,3] ----------------
__global__ __launch_bounds__(256) void k_gemm3(const float* __restrict__ H, const float* __restrict__ W,
                                               float* __restrict__ out) {
    __shared__ float Ws[128 * 3];
    int t = threadIdx.x;
    for (int j = t; j < 384; j += 256) Ws[j] = W[j];
    __syncthreads();
    int i = blockIdx.x * 256 + t;
    if (i >= N_NODES) return;
    float a0 = 0.f, a1 = 0.f, a2 = 0.f;
#pragma unroll
    for (int k = 0; k < 128; k += 4) {
        float4 v = *(const float4*)&H[(size_t)i * 128 + k];
        a0 += v.x * Ws[(k + 0) * 3 + 0] + v.y * Ws[(k + 1) * 3 + 0] + v.z * Ws[(k + 2) * 3 + 0] + v.w * Ws[(k + 3) * 3 + 0];
        a1 += v.x * Ws[(k + 0) * 3 + 1] + v.y * Ws[(k + 1) * 3 + 1] + v.z * Ws[(k + 2) * 3 + 1] + v.w * Ws[(k + 3) * 3 + 1];
        a2 += v.x * Ws[(k + 0) * 3 + 2] + v.y * Ws[(k + 1) * 3 + 2] + v.z * Ws[(k + 2) * 3 + 2] + v.w * Ws[(k + 3) * 3 + 2];
    }
    out[(size_t)i * 3 + 0] = a0;
    out[(size_t)i * 3 + 1] = a1;
    out[(size_t)i * 3 + 2] = a2;
}

// ---------------- final aggregation on 3 feats + bias (no relu) ----------------
__global__ __launch_bounds__(256) void k_agg3(const float* __restrict__ xw3, const float* __restrict__ b,
                                              const float* __restrict__ dinv, const int* __restrict__ offs,
                                              const int* __restrict__ csr_src, const float* __restrict__ csr_w,
                                              float* __restrict__ out) {
    int i = blockIdx.x * blockDim.x + threadIdx.x;
    if (i >= N_NODES) return;
    float dn = dinv[i];
    float dn2 = dn * dn;
    float a0 = dn2 * xw3[(size_t)i * 3 + 0];
    float a1 = dn2 * xw3[(size_t)i * 3 + 1];
    float a2 = dn2 * xw3[(size_t)i * 3 + 2];
    int e0 = offs[i], e1 = offs[i + 1];
    for (int e = e0; e < e1; e++) {
        int s = csr_src[e];
        float w = csr_w[e];
        a0 += w * xw3[(size_t)s * 3 + 0];
        a1 += w * xw3[(size_t)s * 3 + 1];
        a2 += w * xw3[(size_t)s * 3 + 2];
    }
    out[(size_t)i * 3 + 0] = a0 + b[0];
    out[(size_t)i * 3 + 1] = a1 + b[1];
    out[(size_t)i * 3 + 2] = a2 + b[2];
}

extern "C" void kernel_launch(void* const* d_in, const int* in_sizes, int n_in,
                              void* d_out, int out_size, void* d_ws, size_t ws_size,
                              hipStream_t stream) {
    const float* x = (const float*)d_in[0];
    const float* sdf = (const float*)d_in[1];
    const unsigned* E = (const unsigned*)d_in[2];
    const float* Wl[6];
    const float* bl[6];
    for (int l = 0; l < 6; l++) {
        Wl[l] = (const float*)d_in[3 + 2 * l];
        bl[l] = (const float*)d_in[4 + 2 * l];
    }

    char* ws = (char*)d_ws;
    size_t off = 0;
    auto alloc = [&](size_t bytes) -> void* {
        void* p = ws + off;
        off += (bytes + 255) / 256 * 256;
        return p;
    };
    int* flag = (int*)alloc(4);
    int* deg = (int*)alloc((size_t)N_NODES * 4);
    int* cursor = (int*)alloc((size_t)N_NODES * 4);
    size_t zbytes = off;  // zero [flag, deg, cursor] in one memset
    int* offs = (int*)alloc((size_t)(N_NODES + 1) * 4);
    int* bsum = (int*)alloc(256 * 4);
    int* csr_src = (int*)alloc((size_t)N_EDGES * 4);
    float* csr_w = (float*)alloc((size_t)N_EDGES * 4);
    float* dinv = (float*)alloc((size_t)N_NODES * 4);
    float* B0 = (float*)alloc((size_t)N_NODES * 128 * 4);
    float* B1 = (float*)alloc((size_t)N_NODES * 128 * 4);
    // g6 / xw3 are never live while B1 holds data -> alias into B1 (ws trim)
    float* g6 = B1;
    float* xw3 = B1;

    hipMemsetAsync(d_ws, 0, zbytes, stream);

    k_detect<<<16, 256, 0, stream>>>(E, flag);
    k_count<<<(N_EDGES + 255) / 256, 256, 0, stream>>>(E, flag, deg);
    int nb = (N_NODES + 1023) / 1024;  // 98
    k_scan1<<<nb, 256, 0, stream>>>(deg, offs, bsum, dinv);
    k_scan2<<<1, 256, 0, stream>>>(bsum, nb);
    k_scan3<<<(N_NODES + 255) / 256, 256, 0, stream>>>(offs, bsum);
    k_fill<<<(N_EDGES + 255) / 256, 256, 0, stream>>>(E, flag, dinv, offs, cursor, csr_src, csr_w);

    // layer 0: aggregate (6-wide) then GEMM 6->128 + bias + relu
    k_agg6<<<(N_NODES + 255) / 256, 256, 0, stream>>>(x, sdf, dinv, offs, csr_src, csr_w, g6);
    k_gemm6<<<(N_NODES + 1) / 2, 256, 0, stream>>>(g6, Wl[0], bl[0], B0);

    // layers 1..4: GEMM 128->128 then aggregate + bias + relu
    for (int l = 1; l <= 4; l++) {
        k_gemm128<<<(N_NODES + 63) / 64, 256, 0, stream>>>(B0, Wl[l], B1);
        k_agg128<<<(N_NODES + 3) / 4, 256, 0, stream>>>(B1, bl[l], dinv, offs, csr_src, csr_w, B0);
    }

    // layer 5: GEMM 128->3 then aggregate + bias (no relu)
    k_gemm3<<<(N_NODES + 255) / 256, 256, 0, stream>>>(B0, Wl[5], xw3);
    k_agg3<<<(N_NODES + 255) / 256, 256, 0, stream>>>(xw3, bl[5], dinv, offs, csr_src, csr_w, (float*)d_out);
}